// Round 27
// baseline (245.452 us; speedup 1.0000x reference)
//
#include <hip/hip_runtime.h>
#include <hip/hip_bf16.h>
#include <stdint.h>

typedef __bf16 bf16_t;
typedef __bf16 bf16x8 __attribute__((ext_vector_type(8)));
typedef __bf16 bf16x4 __attribute__((ext_vector_type(4)));
typedef float f32x4 __attribute__((ext_vector_type(4)));

static constexpr int TT = 2048, CC = 1024;

__device__ __forceinline__ void gld_lds16(const void* g, void* l) {
  __builtin_amdgcn_global_load_lds((const __attribute__((address_space(1))) void*)g,
                                   (__attribute__((address_space(3))) void*)l, 16, 0, 0);
}

// Prep kernel: six weight transposes (f32 [K][N] -> bf16 [N][K]) AND LN1 in ONE
// dispatch. Blocks [0,12288): transposes. Blocks [12288,16384): LN1 row.
__global__ __launch_bounds__(256) void prep_all(const float* __restrict__ wq,
                                                const float* __restrict__ wk,
                                                const float* __restrict__ wv,
                                                const float* __restrict__ wproj,
                                                const float* __restrict__ w1,
                                                const float* __restrict__ w2,
                                                bf16_t* __restrict__ Bqkv,
                                                bf16_t* __restrict__ Bproj,
                                                bf16_t* __restrict__ B1w,
                                                bf16_t* __restrict__ B2w,
                                                const float* __restrict__ x,
                                                const float* __restrict__ g,
                                                const float* __restrict__ b,
                                                bf16_t* __restrict__ h1out) {
  const int id = blockIdx.x;
  const int tid = threadIdx.x;
  if (id >= 12288) {
    const int row = id - 12288;
    const float4 v = ((const float4*)(x + (size_t)row * CC))[tid];
    float s = v.x + v.y + v.z + v.w;
    float q = v.x * v.x + v.y * v.y + v.z * v.z + v.w * v.w;
#pragma unroll
    for (int off = 1; off < 64; off <<= 1) {
      s += __shfl_xor(s, off);
      q += __shfl_xor(q, off);
    }
    __shared__ float red[8];
    const int wave = tid >> 6, lane = tid & 63;
    if (lane == 0) { red[wave] = s; red[4 + wave] = q; }
    __syncthreads();
    s = red[0] + red[1] + red[2] + red[3];
    q = red[4] + red[5] + red[6] + red[7];
    const float mu = s * (1.0f / CC);
    float var = q * (1.0f / CC) - mu * mu;
    var = fmaxf(var, 0.f);
    const float rstd = rsqrtf(var + 1e-5f);
    const float4 gv = ((const float4*)g)[tid];
    const float4 bv = ((const float4*)b)[tid];
    bf16x4 o;
    o[0] = (bf16_t)((v.x - mu) * rstd * gv.x + bv.x);
    o[1] = (bf16_t)((v.y - mu) * rstd * gv.y + bv.y);
    o[2] = (bf16_t)((v.z - mu) * rstd * gv.z + bv.z);
    o[3] = (bf16_t)((v.w - mu) * rstd * gv.w + bv.w);
    *(bf16x4*)(h1out + (size_t)row * CC + tid * 4) = o;
    return;
  }
  const float* in;
  bf16_t* out;
  int K, N, kb, nb;
  if (id < 3072) {
    const int which = id >> 10;  // 0=wq 1=wk 2=wv
    const int r = id & 1023;
    const int z = r >> 6;        // head batch 0..15
    const int rr = r & 63;
    kb = rr >> 1;
    nb = rr & 1;
    K = 1024; N = 64;
    const float* srcs[3] = {wq, wk, wv};
    in = srcs[which] + (size_t)z * 1024 * 64;
    out = Bqkv + (size_t)which * 1024 * 1024 + (size_t)z * 1024 * 64;
  } else if (id < 4096) {
    const int r = id - 3072;
    kb = r >> 5; nb = r & 31;
    K = 1024; N = 1024;
    in = wproj; out = Bproj;
  } else if (id < 8192) {
    const int r = id - 4096;
    kb = r & 31; nb = r >> 5;
    K = 1024; N = 4096;
    in = w1; out = B1w;
  } else {
    const int r = id - 8192;
    kb = r >> 5; nb = r & 31;
    K = 4096; N = 1024;
    in = w2; out = B2w;
  }
  __shared__ float t[32][33];
  const int tx = tid & 31, ty = tid >> 5;
  const int k0 = kb * 32, n0 = nb * 32;
#pragma unroll
  for (int j = 0; j < 4; ++j)
    t[ty + j * 8][tx] = in[(size_t)(k0 + ty + j * 8) * N + n0 + tx];
  __syncthreads();
#pragma unroll
  for (int j = 0; j < 4; ++j)
    out[(size_t)(n0 + ty + j * 8) * K + k0 + tx] = (bf16_t)t[tx][ty + j * 8];
}

// LayerNorm over C=1024, one block (256 thr) per row, bf16 out (used for LN2)
__global__ __launch_bounds__(256) void ln_f32_bf16(const float* __restrict__ x,
                                                   const float* __restrict__ g,
                                                   const float* __restrict__ b,
                                                   bf16_t* __restrict__ out) {
  const int row = blockIdx.x;
  const int tid = threadIdx.x;
  const float4 v = ((const float4*)(x + (size_t)row * CC))[tid];
  float s = v.x + v.y + v.z + v.w;
  float q = v.x * v.x + v.y * v.y + v.z * v.z + v.w * v.w;
#pragma unroll
  for (int off = 1; off < 64; off <<= 1) {
    s += __shfl_xor(s, off);
    q += __shfl_xor(q, off);
  }
  __shared__ float red[8];
  const int wave = tid >> 6, lane = tid & 63;
  if (lane == 0) { red[wave] = s; red[4 + wave] = q; }
  __syncthreads();
  s = red[0] + red[1] + red[2] + red[3];
  q = red[4] + red[5] + red[6] + red[7];
  const float mu = s * (1.0f / CC);
  float var = q * (1.0f / CC) - mu * mu;
  var = fmaxf(var, 0.f);
  const float rstd = rsqrtf(var + 1e-5f);
  const float4 gv = ((const float4*)g)[tid];
  const float4 bv = ((const float4*)b)[tid];
  bf16x4 o;
  o[0] = (bf16_t)((v.x - mu) * rstd * gv.x + bv.x);
  o[1] = (bf16_t)((v.y - mu) * rstd * gv.y + bv.y);
  o[2] = (bf16_t)((v.z - mu) * rstd * gv.z + bv.z);
  o[3] = (bf16_t)((v.w - mu) * rstd * gv.w + bv.w);
  *(bf16x4*)(out + (size_t)row * CC + tid * 4) = o;
}

// C = A[M,K] @ Bt[N,K]^T ; BM x BN tile, BK=64, NW waves, DEPTH-buffered.
// NW=4: 2x2 wave grid. NW=8: 2x4 (512 thr, 16 waves/CU at 2 blocks/CU).
// XCD swizzle (T1), chunk XOR-swizzle (rule #21, conflict-free).
// EPI: 0 bf16; 1 bf16 relu(acc+bias); 2 f32 acc+bias+res; 3 bf16 + V-transpose.
template <int EPI, int BM, int BN, int DEPTH, int NW>
__global__ __launch_bounds__(NW * 64) void gemm_bt(const bf16_t* __restrict__ A,
                                                   const bf16_t* __restrict__ Bt,
                                                   void* __restrict__ Cout,
                                                   const float* __restrict__ bias,
                                                   const float* __restrict__ res,
                                                   bf16_t* __restrict__ vt,
                                                   int M, int N, int K) {
  constexpr int WSN = (NW == 8) ? 4 : 2;
  constexpr int WM = BM / 2, WN = BN / WSN;
  constexpr int MF = WM / 16, NF = WN / 16;
  constexpr int WROWS = NW * 8;
  constexpr int NA = BM / WROWS, NB = BN / WROWS;
  __shared__ alignas(16) bf16_t As[DEPTH][BM * 64];
  __shared__ alignas(16) bf16_t Bs[DEPTH][BN * 64];
  const int tid = threadIdx.x;
  const int wave = tid >> 6, lane = tid & 63;
  const int lr = lane & 15, lg = lane >> 4;
  const int wm = wave / WSN, wn = wave % WSN;

  const int gx = gridDim.x;
  const int nwg = gx * gridDim.y;
  const int orig = (int)blockIdx.y * gx + (int)blockIdx.x;
  const int wgid = (orig & 7) * (nwg >> 3) + (orig >> 3);
  const int tm0 = (wgid / gx) * BM, tn0 = (wgid % gx) * BN;

  const int sr = lane >> 3;
  const int scs = (lane & 7) ^ sr;
  const bf16_t* Ag[NA];
#pragma unroll
  for (int i = 0; i < NA; ++i)
    Ag[i] = A + (size_t)(tm0 + i * WROWS + wave * 8 + sr) * K + scs * 8;
  const bf16_t* Bg[NB];
#pragma unroll
  for (int i = 0; i < NB; ++i)
    Bg[i] = Bt + (size_t)(tn0 + i * WROWS + wave * 8 + sr) * K + scs * 8;

  auto STAGE = [&](int k0, int buf) {
#pragma unroll
    for (int i = 0; i < NA; ++i)
      gld_lds16(Ag[i] + k0, &As[buf][(i * WROWS + wave * 8) * 64]);
#pragma unroll
    for (int i = 0; i < NB; ++i)
      gld_lds16(Bg[i] + k0, &Bs[buf][(i * WROWS + wave * 8) * 64]);
  };

  f32x4 acc[MF][NF] = {};
  const int NT = K >> 6;

  STAGE(0, 0);
  asm volatile("s_waitcnt vmcnt(0)" ::: "memory");
  __builtin_amdgcn_s_barrier();

  for (int t = 0; t < NT; ++t) {
    const int cur = t % DEPTH;
    const bf16_t* Ac = As[cur];
    const bf16_t* Bc = Bs[cur];
    const bool more = (t + DEPTH - 1) < NT;
    if (more) STAGE((t + DEPTH - 1) << 6, (t + DEPTH - 1) % DEPTH);

    __builtin_amdgcn_s_setprio(1);
#pragma unroll
    for (int kk = 0; kk < 2; ++kk) {
      const int ch = ((kk * 4 + lg) ^ (lr & 7)) * 8;
      bf16x8 af[MF], bfr[NF];
#pragma unroll
      for (int n = 0; n < NF; ++n)
        bfr[n] = *(const bf16x8*)&Bc[(wn * WN + n * 16 + lr) * 64 + ch];
#pragma unroll
      for (int m = 0; m < MF; ++m)
        af[m] = *(const bf16x8*)&Ac[(wm * WM + m * 16 + lr) * 64 + ch];
#pragma unroll
      for (int m = 0; m < MF; ++m)
#pragma unroll
        for (int n = 0; n < NF; ++n)
          acc[m][n] =
              __builtin_amdgcn_mfma_f32_16x16x32_bf16(af[m], bfr[n], acc[m][n], 0, 0, 0);
    }
    __builtin_amdgcn_s_setprio(0);
    asm volatile("s_waitcnt vmcnt(0)" ::: "memory");
    __builtin_amdgcn_sched_barrier(0);
    __builtin_amdgcn_s_barrier();
  }

#pragma unroll
  for (int m = 0; m < MF; ++m) {
#pragma unroll
    for (int i = 0; i < 4; ++i) {
      const int row = tm0 + wm * WM + m * 16 + lg * 4 + i;
#pragma unroll
      for (int n = 0; n < NF; ++n) {
        const int col = tn0 + wn * WN + n * 16 + lr;
        float v = acc[m][n][i];
        if (EPI == 1) v = fmaxf(v + bias[col], 0.f);
        if (EPI == 2) v = v + bias[col] + res[(size_t)row * N + col];
        if (EPI == 2) {
          ((float*)Cout)[(size_t)row * N + col] = v;
        } else if (EPI == 3) {
          if (col >= 2048) {
            const int hd = col - 2048;  // h*64 + d
            const size_t vidx =
                ((size_t)((row >> 11) * 16 + (hd >> 6)) * 64 + (hd & 63)) * TT + (row & (TT - 1));
            vt[vidx] = (bf16_t)v;
          } else {
            ((bf16_t*)Cout)[(size_t)row * N + col] = (bf16_t)v;
          }
        } else {
          ((bf16_t*)Cout)[(size_t)row * N + col] = (bf16_t)v;
        }
      }
    }
  }
}

// Flash attention, causal, D=64, T=2048. R27: slim-LDS variant -- KVBLK=64,
// K [64][72] + V^T [64][72] + P [4][16][72] = 27.6KB -> 5 blocks/CU (20 waves/CU)
// for this latency-bound kernel (both pipes <25% busy at 3 blocks/CU).
// LPT grid, chunk-skip, defer-max THR=8, deferred l-reduce, Q pre-scaled 2^-5.
__global__ __launch_bounds__(256, 5) void attn_fwd(const bf16_t* __restrict__ qkv,
                                                   const bf16_t* __restrict__ Vt,
                                                   bf16_t* __restrict__ O) {
  const int bh = blockIdx.x;
  const int bb = bh >> 4, hh = bh & 15;
  const int qt = 31 - (int)blockIdx.y;  // LPT: heaviest first
  const int qbase = qt * 64;
  const int tid = threadIdx.x;
  const int wave = tid >> 6, lane = tid & 63;
  const int lr = lane & 15, lg = lane >> 4;
  const bf16_t* Qp = qkv + (size_t)bb * TT * 3072 + hh * 64;
  const bf16_t* Kp = Qp + 1024;
  const bf16_t* Vh = Vt + (size_t)bh * 64 * TT;

  constexpr int KLP = 72;   // K tile [64 s][72]
  constexpr int VLP = 72;   // V^T tile [64 d][72]
  constexpr int PLP = 72;   // P tile [16 q][72] per wave
  __shared__ alignas(16) bf16_t Klds[64 * KLP];
  __shared__ alignas(16) bf16_t Vlds[64 * VLP];
  __shared__ alignas(16) bf16_t PlS[4][16 * PLP];
  bf16_t* Pw = PlS[wave];

  // staging (4 waves, 64-s tile): K rows wave*16 + i*8 + (lane>>3), chunk (lane&7)*8
  //                               V rows wave*16 + i*8 + (lane>>3), chunk (lane&7)*8
  const int ksr = wave * 16 + (lane >> 3);
  const int ksc = (lane & 7) * 8;

  const int qrow = qbase + wave * 16;
  bf16x8 qf0, qf1;
  {
    const bf16x8 a = *(const bf16x8*)(Qp + (size_t)(qrow + lr) * 3072 + lg * 8);
    const bf16x8 b = *(const bf16x8*)(Qp + (size_t)(qrow + lr) * 3072 + 32 + lg * 8);
#pragma unroll
    for (int j = 0; j < 8; ++j) {
      qf0[j] = (bf16_t)((float)a[j] * 0.03125f);
      qf1[j] = (bf16_t)((float)b[j] * 0.03125f);
    }
  }

  f32x4 oacc[4] = {};
  float m_r[4], l_r[4];
#pragma unroll
  for (int i = 0; i < 4; ++i) { m_r[i] = -1e38f; l_r[i] = 0.f; }

  bf16x8 kpre[2], vpre[2];
#pragma unroll
  for (int i = 0; i < 2; ++i) {
    kpre[i] = *(const bf16x8*)(Kp + (size_t)(ksr + i * 8) * 3072 + ksc);
    vpre[i] = *(const bf16x8*)(Vh + (size_t)(ksr + i * 8) * TT + ksc);
  }
#pragma unroll
  for (int i = 0; i < 2; ++i) {
    *(bf16x8*)&Klds[(ksr + i * 8) * KLP + ksc] = kpre[i];
    *(bf16x8*)&Vlds[(ksr + i * 8) * VLP + ksc] = vpre[i];
  }
  __syncthreads();

  const int nt = qt + 1;
  for (int t = 0; t < nt; ++t) {
    const int s0 = t * 64;
    const int sn = (t + 1 < nt) ? s0 + 64 : s0;
#pragma unroll
    for (int i = 0; i < 2; ++i) {
      kpre[i] = *(const bf16x8*)(Kp + (size_t)(sn + ksr + i * 8) * 3072 + ksc);
      vpre[i] = *(const bf16x8*)(Vh + (size_t)(ksr + i * 8) * TT + sn + ksc);
    }

    const int u = (qrow - s0) >> 4;       // wave-uniform
    const int cmc = min(u | 1, 3);        // last computed chunk (odd, <=3)

    // ---- QK^T over up to 64 s ----
    float P[4][4];
    __builtin_amdgcn_s_setprio(1);
#pragma unroll
    for (int ct = 0; ct < 4; ++ct) {
      if (ct <= cmc) {
        const bf16x8 kf0 = *(const bf16x8*)&Klds[(ct * 16 + lr) * KLP + lg * 8];
        const bf16x8 kf1 = *(const bf16x8*)&Klds[(ct * 16 + lr) * KLP + 32 + lg * 8];
        f32x4 z = {};
        z = __builtin_amdgcn_mfma_f32_16x16x32_bf16(qf0, kf0, z, 0, 0, 0);
        z = __builtin_amdgcn_mfma_f32_16x16x32_bf16(qf1, kf1, z, 0, 0, 0);
        if (ct >= u) {
          const int sg = s0 + ct * 16 + lr;
#pragma unroll
          for (int i = 0; i < 4; ++i)
            P[ct][i] = (sg > qrow + lg * 4 + i) ? -1e30f : z[i];
        } else {
#pragma unroll
          for (int i = 0; i < 4; ++i) P[ct][i] = z[i];
        }
      } else {
#pragma unroll
        for (int i = 0; i < 4; ++i) P[ct][i] = -1e30f;
      }
    }
    __builtin_amdgcn_s_setprio(0);

    // ---- local max + defer-max ----
    float lmax[4];
#pragma unroll
    for (int i = 0; i < 4; ++i)
      lmax[i] = fmaxf(fmaxf(P[0][i], P[1][i]), fmaxf(P[2][i], P[3][i]));
    const bool ok = (lmax[0] <= m_r[0] + 8.f) && (lmax[1] <= m_r[1] + 8.f) &&
                    (lmax[2] <= m_r[2] + 8.f) && (lmax[3] <= m_r[3] + 8.f);
    if (!__all(ok)) {
      float rm[4] = {lmax[0], lmax[1], lmax[2], lmax[3]};
#pragma unroll
      for (int off = 1; off < 16; off <<= 1)
#pragma unroll
        for (int i = 0; i < 4; ++i) rm[i] = fmaxf(rm[i], __shfl_xor(rm[i], off));
#pragma unroll
      for (int i = 0; i < 4; ++i) {
        const float mn = fmaxf(m_r[i], rm[i]);
        const float alpha = __expf(m_r[i] - mn);
        m_r[i] = mn;
        l_r[i] *= alpha;
#pragma unroll
        for (int db = 0; db < 4; ++db) oacc[db][i] *= alpha;
      }
    }

    // ---- exp + per-lane partial l ----
#pragma unroll
    for (int i = 0; i < 4; ++i) {
      float ls = 0.f;
#pragma unroll
      for (int ct = 0; ct < 4; ++ct) {
        const float p = __expf(P[ct][i] - m_r[i]);
        P[ct][i] = p;
        ls += p;
      }
      l_r[i] += ls;
    }

    // ---- P -> LDS ([16][72], q-swizzled cols; 2-way writes = free) ----
#pragma unroll
    for (int ct = 0; ct < 4; ++ct) {
      if (ct <= cmc) {
#pragma unroll
        for (int i = 0; i < 4; ++i) {
          const int q = lg * 4 + i;
          const int col = (ct * 16 + lr) ^ ((lg >> 1) << 4);
          Pw[q * PLP + col] = (bf16_t)P[ct][i];
        }
      }
    }
    asm volatile("s_waitcnt lgkmcnt(0)" ::: "memory");
    __builtin_amdgcn_sched_barrier(0);

    // ---- PV (kc clipped) ----
    const int kcm = cmc >> 1;
    __builtin_amdgcn_s_setprio(1);
#pragma unroll
    for (int kc = 0; kc < 2; ++kc) {
      if (kc <= kcm) {
        const bf16x8 pf =
            *(const bf16x8*)&Pw[lr * PLP + ((kc * 32 + lg * 8) ^ ((lr >> 3) << 4))];
#pragma unroll
        for (int db = 0; db < 4; ++db) {
          const bf16x8 vf = *(const bf16x8*)&Vlds[(db * 16 + lr) * VLP + kc * 32 + lg * 8];
          oacc[db] = __builtin_amdgcn_mfma_f32_16x16x32_bf16(pf, vf, oacc[db], 0, 0, 0);
        }
      }
    }
    __builtin_amdgcn_s_setprio(0);

    // ---- publish next tile ----
    if (t + 1 < nt) {
      __syncthreads();
#pragma unroll
      for (int i = 0; i < 2; ++i) {
        *(bf16x8*)&Klds[(ksr + i * 8) * KLP + ksc] = kpre[i];
        *(bf16x8*)&Vlds[(ksr + i * 8) * VLP + ksc] = vpre[i];
      }
      __syncthreads();
    }
  }

  // epilogue: reduce l across the 16 s-owner lanes, then store O = oacc/l
#pragma unroll
  for (int off = 1; off < 16; off <<= 1)
#pragma unroll
    for (int i = 0; i < 4; ++i) l_r[i] += __shfl_xor(l_r[i], off);

  bf16_t* Op = O + ((size_t)bb * TT + qrow) * CC + hh * 64;
#pragma unroll
  for (int i = 0; i < 4; ++i) {
    const float rl = 1.0f / l_r[i];
#pragma unroll
    for (int db = 0; db < 4; ++db)
      Op[(size_t)(lg * 4 + i) * CC + db * 16 + lr] = (bf16_t)(oacc[db][i] * rl);
  }
}

extern "C" void kernel_launch(void* const* d_in, const int* in_sizes, int n_in,
                              void* d_out, int out_size, void* d_ws, size_t ws_size,
                              hipStream_t stream) {
  const float* x      = (const float*)d_in[0];
  const float* wq     = (const float*)d_in[1];
  const float* wk     = (const float*)d_in[2];
  const float* wv     = (const float*)d_in[3];
  const float* w_proj = (const float*)d_in[4];
  const float* b_proj = (const float*)d_in[5];
  const float* w1     = (const float*)d_in[6];
  const float* b1     = (const float*)d_in[7];
  const float* w2     = (const float*)d_in[8];
  const float* b2     = (const float*)d_in[9];
  const float* ln1_g  = (const float*)d_in[10];
  const float* ln1_b  = (const float*)d_in[11];
  const float* ln2_g  = (const float*)d_in[12];
  const float* ln2_b  = (const float*)d_in[13];

  char* ws = (char*)d_ws;
  const size_t MB = 1024 * 1024;
  bf16_t* h1    = (bf16_t*)(ws + 0);         // 8 MB  [4096][1024]
  bf16_t* Bqkv  = (bf16_t*)(ws + 8 * MB);    // 6 MB  [3072][1024]
  bf16_t* Bproj = (bf16_t*)(ws + 14 * MB);   // 2 MB  [1024][1024]
  bf16_t* B1w   = (bf16_t*)(ws + 16 * MB);   // 8 MB  [4096][1024]
  bf16_t* B2w   = (bf16_t*)(ws + 24 * MB);   // 8 MB  [1024][4096]
  bf16_t* qkv   = (bf16_t*)(ws + 32 * MB);   // 24 MB [4096][3072] (V region unused)
  bf16_t* Obuf  = (bf16_t*)(ws + 56 * MB);   // 8 MB  [4096][1024]
  float*  res1  = (float*)(ws + 64 * MB);    // 16 MB [4096][1024], written AFTER attn
  bf16_t* Vt    = (bf16_t*)(ws + 64 * MB);   // 16 MB [32][64][2048], dead once attn done
  bf16_t* h2    = (bf16_t*)(ws + 80 * MB);   // 8 MB  [4096][1024]
  bf16_t* a1    = (bf16_t*)(ws + 32 * MB);   // 32 MB [4096][4096], reuses qkv+Obuf
  float*  outp  = (float*)d_out;

  dim3 blk(256), blk512(512);
  prep_all<<<dim3(16384), blk, 0, stream>>>(wq, wk, wv, w_proj, w1, w2,
                                            Bqkv, Bproj, B1w, B2w,
                                            x, ln1_g, ln1_b, h1);

  gemm_bt<3, 128, 128, 2, 8><<<dim3(24, 32), blk512, 0, stream>>>(h1, Bqkv, qkv, nullptr,
                                                                  nullptr, Vt, 4096, 3072, 1024);
  attn_fwd<<<dim3(32, 32), blk, 0, stream>>>(qkv, Vt, Obuf);
  gemm_bt<2, 64, 64, 2, 4><<<dim3(16, 64), blk, 0, stream>>>(Obuf, Bproj, res1, b_proj, x,
                                                             nullptr, 4096, 1024, 1024);
  ln_f32_bf16<<<dim3(4096), blk, 0, stream>>>(res1, ln2_g, ln2_b, h2);
  gemm_bt<1, 128, 128, 2, 8><<<dim3(32, 32), blk512, 0, stream>>>(h2, B1w, a1, b1, nullptr,
                                                                  nullptr, 4096, 4096, 1024);
  gemm_bt<2, 64, 64, 2, 4><<<dim3(16, 64), blk, 0, stream>>>(a1, B2w, outp, b2, res1,
                                                             nullptr, 4096, 1024, 4096);
}

// Round 28
// 237.525 us; speedup vs baseline: 1.0334x; 1.0334x over previous
//
#include <hip/hip_runtime.h>
#include <hip/hip_bf16.h>
#include <stdint.h>

typedef __bf16 bf16_t;
typedef __bf16 bf16x8 __attribute__((ext_vector_type(8)));
typedef __bf16 bf16x4 __attribute__((ext_vector_type(4)));
typedef float f32x4 __attribute__((ext_vector_type(4)));

static constexpr int TT = 2048, CC = 1024;

__device__ __forceinline__ void gld_lds16(const void* g, void* l) {
  __builtin_amdgcn_global_load_lds((const __attribute__((address_space(1))) void*)g,
                                   (__attribute__((address_space(3))) void*)l, 16, 0, 0);
}

// Prep kernel: six weight transposes (f32 [K][N] -> bf16 [N][K]) AND LN1 in ONE
// dispatch. Blocks [0,12288): transposes. Blocks [12288,16384): LN1 row.
__global__ __launch_bounds__(256) void prep_all(const float* __restrict__ wq,
                                                const float* __restrict__ wk,
                                                const float* __restrict__ wv,
                                                const float* __restrict__ wproj,
                                                const float* __restrict__ w1,
                                                const float* __restrict__ w2,
                                                bf16_t* __restrict__ Bqkv,
                                                bf16_t* __restrict__ Bproj,
                                                bf16_t* __restrict__ B1w,
                                                bf16_t* __restrict__ B2w,
                                                const float* __restrict__ x,
                                                const float* __restrict__ g,
                                                const float* __restrict__ b,
                                                bf16_t* __restrict__ h1out) {
  const int id = blockIdx.x;
  const int tid = threadIdx.x;
  if (id >= 12288) {
    const int row = id - 12288;
    const float4 v = ((const float4*)(x + (size_t)row * CC))[tid];
    float s = v.x + v.y + v.z + v.w;
    float q = v.x * v.x + v.y * v.y + v.z * v.z + v.w * v.w;
#pragma unroll
    for (int off = 1; off < 64; off <<= 1) {
      s += __shfl_xor(s, off);
      q += __shfl_xor(q, off);
    }
    __shared__ float red[8];
    const int wave = tid >> 6, lane = tid & 63;
    if (lane == 0) { red[wave] = s; red[4 + wave] = q; }
    __syncthreads();
    s = red[0] + red[1] + red[2] + red[3];
    q = red[4] + red[5] + red[6] + red[7];
    const float mu = s * (1.0f / CC);
    float var = q * (1.0f / CC) - mu * mu;
    var = fmaxf(var, 0.f);
    const float rstd = rsqrtf(var + 1e-5f);
    const float4 gv = ((const float4*)g)[tid];
    const float4 bv = ((const float4*)b)[tid];
    bf16x4 o;
    o[0] = (bf16_t)((v.x - mu) * rstd * gv.x + bv.x);
    o[1] = (bf16_t)((v.y - mu) * rstd * gv.y + bv.y);
    o[2] = (bf16_t)((v.z - mu) * rstd * gv.z + bv.z);
    o[3] = (bf16_t)((v.w - mu) * rstd * gv.w + bv.w);
    *(bf16x4*)(h1out + (size_t)row * CC + tid * 4) = o;
    return;
  }
  const float* in;
  bf16_t* out;
  int K, N, kb, nb;
  if (id < 3072) {
    const int which = id >> 10;  // 0=wq 1=wk 2=wv
    const int r = id & 1023;
    const int z = r >> 6;        // head batch 0..15
    const int rr = r & 63;
    kb = rr >> 1;
    nb = rr & 1;
    K = 1024; N = 64;
    const float* srcs[3] = {wq, wk, wv};
    in = srcs[which] + (size_t)z * 1024 * 64;
    out = Bqkv + (size_t)which * 1024 * 1024 + (size_t)z * 1024 * 64;
  } else if (id < 4096) {
    const int r = id - 3072;
    kb = r >> 5; nb = r & 31;
    K = 1024; N = 1024;
    in = wproj; out = Bproj;
  } else if (id < 8192) {
    const int r = id - 4096;
    kb = r & 31; nb = r >> 5;
    K = 1024; N = 4096;
    in = w1; out = B1w;
  } else {
    const int r = id - 8192;
    kb = r >> 5; nb = r & 31;
    K = 4096; N = 1024;
    in = w2; out = B2w;
  }
  __shared__ float t[32][33];
  const int tx = tid & 31, ty = tid >> 5;
  const int k0 = kb * 32, n0 = nb * 32;
#pragma unroll
  for (int j = 0; j < 4; ++j)
    t[ty + j * 8][tx] = in[(size_t)(k0 + ty + j * 8) * N + n0 + tx];
  __syncthreads();
#pragma unroll
  for (int j = 0; j < 4; ++j)
    out[(size_t)(n0 + ty + j * 8) * K + k0 + tx] = (bf16_t)t[tx][ty + j * 8];
}

// LayerNorm over C=1024, one block (256 thr) per row, bf16 out (used for LN2)
__global__ __launch_bounds__(256) void ln_f32_bf16(const float* __restrict__ x,
                                                   const float* __restrict__ g,
                                                   const float* __restrict__ b,
                                                   bf16_t* __restrict__ out) {
  const int row = blockIdx.x;
  const int tid = threadIdx.x;
  const float4 v = ((const float4*)(x + (size_t)row * CC))[tid];
  float s = v.x + v.y + v.z + v.w;
  float q = v.x * v.x + v.y * v.y + v.z * v.z + v.w * v.w;
#pragma unroll
  for (int off = 1; off < 64; off <<= 1) {
    s += __shfl_xor(s, off);
    q += __shfl_xor(q, off);
  }
  __shared__ float red[8];
  const int wave = tid >> 6, lane = tid & 63;
  if (lane == 0) { red[wave] = s; red[4 + wave] = q; }
  __syncthreads();
  s = red[0] + red[1] + red[2] + red[3];
  q = red[4] + red[5] + red[6] + red[7];
  const float mu = s * (1.0f / CC);
  float var = q * (1.0f / CC) - mu * mu;
  var = fmaxf(var, 0.f);
  const float rstd = rsqrtf(var + 1e-5f);
  const float4 gv = ((const float4*)g)[tid];
  const float4 bv = ((const float4*)b)[tid];
  bf16x4 o;
  o[0] = (bf16_t)((v.x - mu) * rstd * gv.x + bv.x);
  o[1] = (bf16_t)((v.y - mu) * rstd * gv.y + bv.y);
  o[2] = (bf16_t)((v.z - mu) * rstd * gv.z + bv.z);
  o[3] = (bf16_t)((v.w - mu) * rstd * gv.w + bv.w);
  *(bf16x4*)(out + (size_t)row * CC + tid * 4) = o;
}

// C = A[M,K] @ Bt[N,K]^T ; BM x BN tile, BK=64, NW waves, DEPTH-buffered.
// NW=4: 2x2 wave grid. NW=8: 2x4 (512 thr, 16 waves/CU at 2 blocks/CU).
// XCD swizzle (T1), chunk XOR-swizzle (rule #21, conflict-free).
// EPI: 0 bf16; 1 bf16 relu(acc+bias); 2 f32 acc+bias+res; 3 bf16 + V-transpose.
template <int EPI, int BM, int BN, int DEPTH, int NW>
__global__ __launch_bounds__(NW * 64) void gemm_bt(const bf16_t* __restrict__ A,
                                                   const bf16_t* __restrict__ Bt,
                                                   void* __restrict__ Cout,
                                                   const float* __restrict__ bias,
                                                   const float* __restrict__ res,
                                                   bf16_t* __restrict__ vt,
                                                   int M, int N, int K) {
  constexpr int WSN = (NW == 8) ? 4 : 2;
  constexpr int WM = BM / 2, WN = BN / WSN;
  constexpr int MF = WM / 16, NF = WN / 16;
  constexpr int WROWS = NW * 8;
  constexpr int NA = BM / WROWS, NB = BN / WROWS;
  __shared__ alignas(16) bf16_t As[DEPTH][BM * 64];
  __shared__ alignas(16) bf16_t Bs[DEPTH][BN * 64];
  const int tid = threadIdx.x;
  const int wave = tid >> 6, lane = tid & 63;
  const int lr = lane & 15, lg = lane >> 4;
  const int wm = wave / WSN, wn = wave % WSN;

  const int gx = gridDim.x;
  const int nwg = gx * gridDim.y;
  const int orig = (int)blockIdx.y * gx + (int)blockIdx.x;
  const int wgid = (orig & 7) * (nwg >> 3) + (orig >> 3);
  const int tm0 = (wgid / gx) * BM, tn0 = (wgid % gx) * BN;

  const int sr = lane >> 3;
  const int scs = (lane & 7) ^ sr;
  const bf16_t* Ag[NA];
#pragma unroll
  for (int i = 0; i < NA; ++i)
    Ag[i] = A + (size_t)(tm0 + i * WROWS + wave * 8 + sr) * K + scs * 8;
  const bf16_t* Bg[NB];
#pragma unroll
  for (int i = 0; i < NB; ++i)
    Bg[i] = Bt + (size_t)(tn0 + i * WROWS + wave * 8 + sr) * K + scs * 8;

  auto STAGE = [&](int k0, int buf) {
#pragma unroll
    for (int i = 0; i < NA; ++i)
      gld_lds16(Ag[i] + k0, &As[buf][(i * WROWS + wave * 8) * 64]);
#pragma unroll
    for (int i = 0; i < NB; ++i)
      gld_lds16(Bg[i] + k0, &Bs[buf][(i * WROWS + wave * 8) * 64]);
  };

  f32x4 acc[MF][NF] = {};
  const int NT = K >> 6;

  STAGE(0, 0);
  asm volatile("s_waitcnt vmcnt(0)" ::: "memory");
  __builtin_amdgcn_s_barrier();

  for (int t = 0; t < NT; ++t) {
    const int cur = t % DEPTH;
    const bf16_t* Ac = As[cur];
    const bf16_t* Bc = Bs[cur];
    const bool more = (t + DEPTH - 1) < NT;
    if (more) STAGE((t + DEPTH - 1) << 6, (t + DEPTH - 1) % DEPTH);

    __builtin_amdgcn_s_setprio(1);
#pragma unroll
    for (int kk = 0; kk < 2; ++kk) {
      const int ch = ((kk * 4 + lg) ^ (lr & 7)) * 8;
      bf16x8 af[MF], bfr[NF];
#pragma unroll
      for (int n = 0; n < NF; ++n)
        bfr[n] = *(const bf16x8*)&Bc[(wn * WN + n * 16 + lr) * 64 + ch];
#pragma unroll
      for (int m = 0; m < MF; ++m)
        af[m] = *(const bf16x8*)&Ac[(wm * WM + m * 16 + lr) * 64 + ch];
#pragma unroll
      for (int m = 0; m < MF; ++m)
#pragma unroll
        for (int n = 0; n < NF; ++n)
          acc[m][n] =
              __builtin_amdgcn_mfma_f32_16x16x32_bf16(af[m], bfr[n], acc[m][n], 0, 0, 0);
    }
    __builtin_amdgcn_s_setprio(0);
    asm volatile("s_waitcnt vmcnt(0)" ::: "memory");
    __builtin_amdgcn_sched_barrier(0);
    __builtin_amdgcn_s_barrier();
  }

#pragma unroll
  for (int m = 0; m < MF; ++m) {
#pragma unroll
    for (int i = 0; i < 4; ++i) {
      const int row = tm0 + wm * WM + m * 16 + lg * 4 + i;
#pragma unroll
      for (int n = 0; n < NF; ++n) {
        const int col = tn0 + wn * WN + n * 16 + lr;
        float v = acc[m][n][i];
        if (EPI == 1) v = fmaxf(v + bias[col], 0.f);
        if (EPI == 2) v = v + bias[col] + res[(size_t)row * N + col];
        if (EPI == 2) {
          ((float*)Cout)[(size_t)row * N + col] = v;
        } else if (EPI == 3) {
          if (col >= 2048) {
            const int hd = col - 2048;  // h*64 + d
            const size_t vidx =
                ((size_t)((row >> 11) * 16 + (hd >> 6)) * 64 + (hd & 63)) * TT + (row & (TT - 1));
            vt[vidx] = (bf16_t)v;
          } else {
            ((bf16_t*)Cout)[(size_t)row * N + col] = (bf16_t)v;
          }
        } else {
          ((bf16_t*)Cout)[(size_t)row * N + col] = (bf16_t)v;
        }
      }
    }
  }
}

// Flash attention, causal, D=64, T=2048 (R16/R24 structure: 4 waves, 64 q-rows/block;
// KVBLK=128; K and V^T cooperatively LDS-staged; best measured config).
__global__ __launch_bounds__(256, 3) void attn_fwd(const bf16_t* __restrict__ qkv,
                                                   const bf16_t* __restrict__ Vt,
                                                   bf16_t* __restrict__ O) {
  const int bh = blockIdx.x;
  const int bb = bh >> 4, hh = bh & 15;
  const int qt = 31 - (int)blockIdx.y;
  const int qbase = qt * 64;
  const int tid = threadIdx.x;
  const int wave = tid >> 6, lane = tid & 63;
  const int lr = lane & 15, lg = lane >> 4;
  const bf16_t* Qp = qkv + (size_t)bb * TT * 3072 + hh * 64;
  const bf16_t* Kp = Qp + 1024;
  const bf16_t* Vh = Vt + (size_t)bh * 64 * TT;

  constexpr int KLP = 72;
  constexpr int VLP = 136;
  constexpr int PLP = 136;
  __shared__ alignas(16) bf16_t Klds[128 * KLP];
  __shared__ alignas(16) bf16_t Vlds[64 * VLP];
  __shared__ alignas(16) bf16_t PlS[4][16 * PLP];
  bf16_t* Pw = PlS[wave];

  const int ksr = wave * 32 + (lane >> 3);
  const int ksc = (lane & 7) * 8;
  const int vsr = wave * 16 + (lane >> 4);
  const int vsc = (lane & 15) * 8;

  const int qrow = qbase + wave * 16;
  bf16x8 qf0, qf1;
  {
    const bf16x8 a = *(const bf16x8*)(Qp + (size_t)(qrow + lr) * 3072 + lg * 8);
    const bf16x8 b = *(const bf16x8*)(Qp + (size_t)(qrow + lr) * 3072 + 32 + lg * 8);
#pragma unroll
    for (int j = 0; j < 8; ++j) {
      qf0[j] = (bf16_t)((float)a[j] * 0.03125f);
      qf1[j] = (bf16_t)((float)b[j] * 0.03125f);
    }
  }

  f32x4 oacc[4] = {};
  float m_r[4], l_r[4];
#pragma unroll
  for (int i = 0; i < 4; ++i) { m_r[i] = -1e38f; l_r[i] = 0.f; }

  bf16x8 kpre[4], vpre[4];
#pragma unroll
  for (int i = 0; i < 4; ++i) {
    kpre[i] = *(const bf16x8*)(Kp + (size_t)(ksr + i * 8) * 3072 + ksc);
    vpre[i] = *(const bf16x8*)(Vh + (size_t)(vsr + i * 4) * TT + vsc);
  }
#pragma unroll
  for (int i = 0; i < 4; ++i) {
    *(bf16x8*)&Klds[(ksr + i * 8) * KLP + ksc] = kpre[i];
    *(bf16x8*)&Vlds[(vsr + i * 4) * VLP + vsc] = vpre[i];
  }
  __syncthreads();

  const int nt = (qt >> 1) + 1;
  for (int t = 0; t < nt; ++t) {
    const int s0 = t * 128;
    const int sn = (t + 1 < nt) ? s0 + 128 : s0;
#pragma unroll
    for (int i = 0; i < 4; ++i) {
      kpre[i] = *(const bf16x8*)(Kp + (size_t)(sn + ksr + i * 8) * 3072 + ksc);
      vpre[i] = *(const bf16x8*)(Vh + (size_t)(vsr + i * 4) * TT + sn + vsc);
    }

    const int u = (qrow - s0) >> 4;
    const int cmc = min(u | 1, 7);

    float P[8][4];
    __builtin_amdgcn_s_setprio(1);
#pragma unroll
    for (int ct = 0; ct < 8; ++ct) {
      if (ct <= cmc) {
        const bf16x8 kf0 = *(const bf16x8*)&Klds[(ct * 16 + lr) * KLP + lg * 8];
        const bf16x8 kf1 = *(const bf16x8*)&Klds[(ct * 16 + lr) * KLP + 32 + lg * 8];
        f32x4 z = {};
        z = __builtin_amdgcn_mfma_f32_16x16x32_bf16(qf0, kf0, z, 0, 0, 0);
        z = __builtin_amdgcn_mfma_f32_16x16x32_bf16(qf1, kf1, z, 0, 0, 0);
        if (ct >= u) {
          const int sg = s0 + ct * 16 + lr;
#pragma unroll
          for (int i = 0; i < 4; ++i)
            P[ct][i] = (sg > qrow + lg * 4 + i) ? -1e30f : z[i];
        } else {
#pragma unroll
          for (int i = 0; i < 4; ++i) P[ct][i] = z[i];
        }
      } else {
#pragma unroll
        for (int i = 0; i < 4; ++i) P[ct][i] = -1e30f;
      }
    }
    __builtin_amdgcn_s_setprio(0);

    float lmax[4];
#pragma unroll
    for (int i = 0; i < 4; ++i) {
      float m0 = fmaxf(fmaxf(P[0][i], P[1][i]), fmaxf(P[2][i], P[3][i]));
      float m1 = fmaxf(fmaxf(P[4][i], P[5][i]), fmaxf(P[6][i], P[7][i]));
      lmax[i] = fmaxf(m0, m1);
    }
    const bool ok = (lmax[0] <= m_r[0] + 8.f) && (lmax[1] <= m_r[1] + 8.f) &&
                    (lmax[2] <= m_r[2] + 8.f) && (lmax[3] <= m_r[3] + 8.f);
    if (!__all(ok)) {
      float rm[4] = {lmax[0], lmax[1], lmax[2], lmax[3]};
#pragma unroll
      for (int off = 1; off < 16; off <<= 1)
#pragma unroll
        for (int i = 0; i < 4; ++i) rm[i] = fmaxf(rm[i], __shfl_xor(rm[i], off));
#pragma unroll
      for (int i = 0; i < 4; ++i) {
        const float mn = fmaxf(m_r[i], rm[i]);
        const float alpha = __expf(m_r[i] - mn);
        m_r[i] = mn;
        l_r[i] *= alpha;
#pragma unroll
        for (int db = 0; db < 4; ++db) oacc[db][i] *= alpha;
      }
    }

#pragma unroll
    for (int i = 0; i < 4; ++i) {
      float ls = 0.f;
#pragma unroll
      for (int ct = 0; ct < 8; ++ct) {
        const float p = __expf(P[ct][i] - m_r[i]);
        P[ct][i] = p;
        ls += p;
      }
      l_r[i] += ls;
    }

#pragma unroll
    for (int ct = 0; ct < 8; ++ct) {
      if (ct <= cmc) {
#pragma unroll
        for (int i = 0; i < 4; ++i) {
          const int q = lg * 4 + i;
          const int col = (ct * 16 + lr) ^ ((lg >> 1) << 4);
          Pw[q * PLP + col] = (bf16_t)P[ct][i];
        }
      }
    }
    asm volatile("s_waitcnt lgkmcnt(0)" ::: "memory");
    __builtin_amdgcn_sched_barrier(0);

    const int kcm = cmc >> 1;
    __builtin_amdgcn_s_setprio(1);
#pragma unroll
    for (int kc = 0; kc < 4; ++kc) {
      if (kc <= kcm) {
        const bf16x8 pf =
            *(const bf16x8*)&Pw[lr * PLP + ((kc * 32 + lg * 8) ^ ((lr >> 3) << 4))];
#pragma unroll
        for (int db = 0; db < 4; ++db) {
          const bf16x8 vf = *(const bf16x8*)&Vlds[(db * 16 + lr) * VLP + kc * 32 + lg * 8];
          oacc[db] = __builtin_amdgcn_mfma_f32_16x16x32_bf16(pf, vf, oacc[db], 0, 0, 0);
        }
      }
    }
    __builtin_amdgcn_s_setprio(0);

    if (t + 1 < nt) {
      __syncthreads();
#pragma unroll
      for (int i = 0; i < 4; ++i) {
        *(bf16x8*)&Klds[(ksr + i * 8) * KLP + ksc] = kpre[i];
        *(bf16x8*)&Vlds[(vsr + i * 4) * VLP + vsc] = vpre[i];
      }
      __syncthreads();
    }
  }

#pragma unroll
  for (int off = 1; off < 16; off <<= 1)
#pragma unroll
    for (int i = 0; i < 4; ++i) l_r[i] += __shfl_xor(l_r[i], off);

  bf16_t* Op = O + ((size_t)bb * TT + qrow) * CC + hh * 64;
#pragma unroll
  for (int i = 0; i < 4; ++i) {
    const float rl = 1.0f / l_r[i];
#pragma unroll
    for (int db = 0; db < 4; ++db)
      Op[(size_t)(lg * 4 + i) * CC + db * 16 + lr] = (bf16_t)(oacc[db][i] * rl);
  }
}

extern "C" void kernel_launch(void* const* d_in, const int* in_sizes, int n_in,
                              void* d_out, int out_size, void* d_ws, size_t ws_size,
                              hipStream_t stream) {
  const float* x      = (const float*)d_in[0];
  const float* wq     = (const float*)d_in[1];
  const float* wk     = (const float*)d_in[2];
  const float* wv     = (const float*)d_in[3];
  const float* w_proj = (const float*)d_in[4];
  const float* b_proj = (const float*)d_in[5];
  const float* w1     = (const float*)d_in[6];
  const float* b1     = (const float*)d_in[7];
  const float* w2     = (const float*)d_in[8];
  const float* b2     = (const float*)d_in[9];
  const float* ln1_g  = (const float*)d_in[10];
  const float* ln1_b  = (const float*)d_in[11];
  const float* ln2_g  = (const float*)d_in[12];
  const float* ln2_b  = (const float*)d_in[13];

  char* ws = (char*)d_ws;
  const size_t MB = 1024 * 1024;
  bf16_t* h1    = (bf16_t*)(ws + 0);         // 8 MB  [4096][1024]
  bf16_t* Bqkv  = (bf16_t*)(ws + 8 * MB);    // 6 MB  [3072][1024]
  bf16_t* Bproj = (bf16_t*)(ws + 14 * MB);   // 2 MB  [1024][1024]
  bf16_t* B1w   = (bf16_t*)(ws + 16 * MB);   // 8 MB  [4096][1024]
  bf16_t* B2w   = (bf16_t*)(ws + 24 * MB);   // 8 MB  [1024][4096]
  bf16_t* qkv   = (bf16_t*)(ws + 32 * MB);   // 24 MB [4096][3072] (V region unused)
  bf16_t* Obuf  = (bf16_t*)(ws + 56 * MB);   // 8 MB  [4096][1024]
  float*  res1  = (float*)(ws + 64 * MB);    // 16 MB [4096][1024], written AFTER attn
  bf16_t* Vt    = (bf16_t*)(ws + 64 * MB);   // 16 MB [32][64][2048], dead once attn done
  bf16_t* h2    = (bf16_t*)(ws + 80 * MB);   // 8 MB  [4096][1024]
  bf16_t* a1    = (bf16_t*)(ws + 32 * MB);   // 32 MB [4096][4096], reuses qkv+Obuf
  float*  outp  = (float*)d_out;

  dim3 blk(256), blk512(512);
  prep_all<<<dim3(16384), blk, 0, stream>>>(wq, wk, wv, w_proj, w1, w2,
                                            Bqkv, Bproj, B1w, B2w,
                                            x, ln1_g, ln1_b, h1);

  gemm_bt<3, 128, 128, 2, 8><<<dim3(24, 32), blk512, 0, stream>>>(h1, Bqkv, qkv, nullptr,
                                                                  nullptr, Vt, 4096, 3072, 1024);
  attn_fwd<<<dim3(32, 32), blk, 0, stream>>>(qkv, Vt, Obuf);
  gemm_bt<2, 64, 64, 2, 4><<<dim3(16, 64), blk, 0, stream>>>(Obuf, Bproj, res1, b_proj, x,
                                                             nullptr, 4096, 1024, 1024);
  ln_f32_bf16<<<dim3(4096), blk, 0, stream>>>(res1, ln2_g, ln2_b, h2);
  gemm_bt<1, 128, 128, 2, 8><<<dim3(32, 32), blk512, 0, stream>>>(h2, B1w, a1, b1, nullptr,
                                                                  nullptr, 4096, 4096, 1024);
  gemm_bt<2, 64, 64, 2, 4><<<dim3(16, 64), blk, 0, stream>>>(a1, B2w, outp, b2, res1,
                                                             nullptr, 4096, 1024, 4096);
}

// Round 29
// 235.635 us; speedup vs baseline: 1.0417x; 1.0080x over previous
//
#include <hip/hip_runtime.h>
#include <hip/hip_bf16.h>
#include <stdint.h>

typedef __bf16 bf16_t;
typedef __bf16 bf16x8 __attribute__((ext_vector_type(8)));
typedef __bf16 bf16x4 __attribute__((ext_vector_type(4)));
typedef float f32x4 __attribute__((ext_vector_type(4)));

static constexpr int TT = 2048, CC = 1024;

__device__ __forceinline__ void gld_lds16(const void* g, void* l) {
  __builtin_amdgcn_global_load_lds((const __attribute__((address_space(1))) void*)g,
                                   (__attribute__((address_space(3))) void*)l, 16, 0, 0);
}

// Prep kernel: six weight transposes (f32 [K][N] -> bf16 [N][K]) AND LN1 in ONE
// dispatch. Blocks [0,12288): transposes. Blocks [12288,16384): LN1 row.
__global__ __launch_bounds__(256) void prep_all(const float* __restrict__ wq,
                                                const float* __restrict__ wk,
                                                const float* __restrict__ wv,
                                                const float* __restrict__ wproj,
                                                const float* __restrict__ w1,
                                                const float* __restrict__ w2,
                                                bf16_t* __restrict__ Bqkv,
                                                bf16_t* __restrict__ Bproj,
                                                bf16_t* __restrict__ B1w,
                                                bf16_t* __restrict__ B2w,
                                                const float* __restrict__ x,
                                                const float* __restrict__ g,
                                                const float* __restrict__ b,
                                                bf16_t* __restrict__ h1out) {
  const int id = blockIdx.x;
  const int tid = threadIdx.x;
  if (id >= 12288) {
    const int row = id - 12288;
    const float4 v = ((const float4*)(x + (size_t)row * CC))[tid];
    float s = v.x + v.y + v.z + v.w;
    float q = v.x * v.x + v.y * v.y + v.z * v.z + v.w * v.w;
#pragma unroll
    for (int off = 1; off < 64; off <<= 1) {
      s += __shfl_xor(s, off);
      q += __shfl_xor(q, off);
    }
    __shared__ float red[8];
    const int wave = tid >> 6, lane = tid & 63;
    if (lane == 0) { red[wave] = s; red[4 + wave] = q; }
    __syncthreads();
    s = red[0] + red[1] + red[2] + red[3];
    q = red[4] + red[5] + red[6] + red[7];
    const float mu = s * (1.0f / CC);
    float var = q * (1.0f / CC) - mu * mu;
    var = fmaxf(var, 0.f);
    const float rstd = rsqrtf(var + 1e-5f);
    const float4 gv = ((const float4*)g)[tid];
    const float4 bv = ((const float4*)b)[tid];
    bf16x4 o;
    o[0] = (bf16_t)((v.x - mu) * rstd * gv.x + bv.x);
    o[1] = (bf16_t)((v.y - mu) * rstd * gv.y + bv.y);
    o[2] = (bf16_t)((v.z - mu) * rstd * gv.z + bv.z);
    o[3] = (bf16_t)((v.w - mu) * rstd * gv.w + bv.w);
    *(bf16x4*)(h1out + (size_t)row * CC + tid * 4) = o;
    return;
  }
  const float* in;
  bf16_t* out;
  int K, N, kb, nb;
  if (id < 3072) {
    const int which = id >> 10;  // 0=wq 1=wk 2=wv
    const int r = id & 1023;
    const int z = r >> 6;        // head batch 0..15
    const int rr = r & 63;
    kb = rr >> 1;
    nb = rr & 1;
    K = 1024; N = 64;
    const float* srcs[3] = {wq, wk, wv};
    in = srcs[which] + (size_t)z * 1024 * 64;
    out = Bqkv + (size_t)which * 1024 * 1024 + (size_t)z * 1024 * 64;
  } else if (id < 4096) {
    const int r = id - 3072;
    kb = r >> 5; nb = r & 31;
    K = 1024; N = 1024;
    in = wproj; out = Bproj;
  } else if (id < 8192) {
    const int r = id - 4096;
    kb = r & 31; nb = r >> 5;
    K = 1024; N = 4096;
    in = w1; out = B1w;
  } else {
    const int r = id - 8192;
    kb = r >> 5; nb = r & 31;
    K = 4096; N = 1024;
    in = w2; out = B2w;
  }
  __shared__ float t[32][33];
  const int tx = tid & 31, ty = tid >> 5;
  const int k0 = kb * 32, n0 = nb * 32;
#pragma unroll
  for (int j = 0; j < 4; ++j)
    t[ty + j * 8][tx] = in[(size_t)(k0 + ty + j * 8) * N + n0 + tx];
  __syncthreads();
#pragma unroll
  for (int j = 0; j < 4; ++j)
    out[(size_t)(n0 + ty + j * 8) * K + k0 + tx] = (bf16_t)t[tx][ty + j * 8];
}

// LayerNorm over C=1024, bf16 INPUT (res1 stored bf16, R29), bf16 out. Used for LN2.
__global__ __launch_bounds__(256) void ln_bf16_bf16(const bf16_t* __restrict__ x,
                                                    const float* __restrict__ g,
                                                    const float* __restrict__ b,
                                                    bf16_t* __restrict__ out) {
  const int row = blockIdx.x;
  const int tid = threadIdx.x;
  const bf16x4 xv = ((const bf16x4*)(x + (size_t)row * CC))[tid];
  const float v0 = (float)xv[0], v1 = (float)xv[1], v2 = (float)xv[2], v3 = (float)xv[3];
  float s = v0 + v1 + v2 + v3;
  float q = v0 * v0 + v1 * v1 + v2 * v2 + v3 * v3;
#pragma unroll
  for (int off = 1; off < 64; off <<= 1) {
    s += __shfl_xor(s, off);
    q += __shfl_xor(q, off);
  }
  __shared__ float red[8];
  const int wave = tid >> 6, lane = tid & 63;
  if (lane == 0) { red[wave] = s; red[4 + wave] = q; }
  __syncthreads();
  s = red[0] + red[1] + red[2] + red[3];
  q = red[4] + red[5] + red[6] + red[7];
  const float mu = s * (1.0f / CC);
  float var = q * (1.0f / CC) - mu * mu;
  var = fmaxf(var, 0.f);
  const float rstd = rsqrtf(var + 1e-5f);
  const float4 gv = ((const float4*)g)[tid];
  const float4 bv = ((const float4*)b)[tid];
  bf16x4 o;
  o[0] = (bf16_t)((v0 - mu) * rstd * gv.x + bv.x);
  o[1] = (bf16_t)((v1 - mu) * rstd * gv.y + bv.y);
  o[2] = (bf16_t)((v2 - mu) * rstd * gv.z + bv.z);
  o[3] = (bf16_t)((v3 - mu) * rstd * gv.w + bv.w);
  *(bf16x4*)(out + (size_t)row * CC + tid * 4) = o;
}

// C = A[M,K] @ Bt[N,K]^T ; BM x BN tile, BK=64, NW waves, DEPTH-buffered.
// NW=4: 2x2 wave grid. NW=8: 2x4 (512 thr, 16 waves/CU at 2 blocks/CU).
// XCD swizzle (T1), chunk XOR-swizzle (rule #21, conflict-free).
// EPI: 0 bf16; 1 bf16 relu(acc+bias); 2 f32 acc+bias+f32res; 3 bf16 + V-transpose;
//      4 f32 acc+bias+bf16res (down); 5 bf16 acc+bias+f32res (proj -> bf16 residual).
template <int EPI, int BM, int BN, int DEPTH, int NW>
__global__ __launch_bounds__(NW * 64) void gemm_bt(const bf16_t* __restrict__ A,
                                                   const bf16_t* __restrict__ Bt,
                                                   void* __restrict__ Cout,
                                                   const float* __restrict__ bias,
                                                   const float* __restrict__ res,
                                                   bf16_t* __restrict__ vt,
                                                   int M, int N, int K) {
  constexpr int WSN = (NW == 8) ? 4 : 2;
  constexpr int WM = BM / 2, WN = BN / WSN;
  constexpr int MF = WM / 16, NF = WN / 16;
  constexpr int WROWS = NW * 8;
  constexpr int NA = BM / WROWS, NB = BN / WROWS;
  __shared__ alignas(16) bf16_t As[DEPTH][BM * 64];
  __shared__ alignas(16) bf16_t Bs[DEPTH][BN * 64];
  const int tid = threadIdx.x;
  const int wave = tid >> 6, lane = tid & 63;
  const int lr = lane & 15, lg = lane >> 4;
  const int wm = wave / WSN, wn = wave % WSN;

  const int gx = gridDim.x;
  const int nwg = gx * gridDim.y;
  const int orig = (int)blockIdx.y * gx + (int)blockIdx.x;
  const int wgid = (orig & 7) * (nwg >> 3) + (orig >> 3);
  const int tm0 = (wgid / gx) * BM, tn0 = (wgid % gx) * BN;

  const int sr = lane >> 3;
  const int scs = (lane & 7) ^ sr;
  const bf16_t* Ag[NA];
#pragma unroll
  for (int i = 0; i < NA; ++i)
    Ag[i] = A + (size_t)(tm0 + i * WROWS + wave * 8 + sr) * K + scs * 8;
  const bf16_t* Bg[NB];
#pragma unroll
  for (int i = 0; i < NB; ++i)
    Bg[i] = Bt + (size_t)(tn0 + i * WROWS + wave * 8 + sr) * K + scs * 8;

  auto STAGE = [&](int k0, int buf) {
#pragma unroll
    for (int i = 0; i < NA; ++i)
      gld_lds16(Ag[i] + k0, &As[buf][(i * WROWS + wave * 8) * 64]);
#pragma unroll
    for (int i = 0; i < NB; ++i)
      gld_lds16(Bg[i] + k0, &Bs[buf][(i * WROWS + wave * 8) * 64]);
  };

  f32x4 acc[MF][NF] = {};
  const int NT = K >> 6;

  STAGE(0, 0);
  asm volatile("s_waitcnt vmcnt(0)" ::: "memory");
  __builtin_amdgcn_s_barrier();

  for (int t = 0; t < NT; ++t) {
    const int cur = t % DEPTH;
    const bf16_t* Ac = As[cur];
    const bf16_t* Bc = Bs[cur];
    const bool more = (t + DEPTH - 1) < NT;
    if (more) STAGE((t + DEPTH - 1) << 6, (t + DEPTH - 1) % DEPTH);

    __builtin_amdgcn_s_setprio(1);
#pragma unroll
    for (int kk = 0; kk < 2; ++kk) {
      const int ch = ((kk * 4 + lg) ^ (lr & 7)) * 8;
      bf16x8 af[MF], bfr[NF];
#pragma unroll
      for (int n = 0; n < NF; ++n)
        bfr[n] = *(const bf16x8*)&Bc[(wn * WN + n * 16 + lr) * 64 + ch];
#pragma unroll
      for (int m = 0; m < MF; ++m)
        af[m] = *(const bf16x8*)&Ac[(wm * WM + m * 16 + lr) * 64 + ch];
#pragma unroll
      for (int m = 0; m < MF; ++m)
#pragma unroll
        for (int n = 0; n < NF; ++n)
          acc[m][n] =
              __builtin_amdgcn_mfma_f32_16x16x32_bf16(af[m], bfr[n], acc[m][n], 0, 0, 0);
    }
    __builtin_amdgcn_s_setprio(0);
    asm volatile("s_waitcnt vmcnt(0)" ::: "memory");
    __builtin_amdgcn_sched_barrier(0);
    __builtin_amdgcn_s_barrier();
  }

#pragma unroll
  for (int m = 0; m < MF; ++m) {
#pragma unroll
    for (int i = 0; i < 4; ++i) {
      const int row = tm0 + wm * WM + m * 16 + lg * 4 + i;
#pragma unroll
      for (int n = 0; n < NF; ++n) {
        const int col = tn0 + wn * WN + n * 16 + lr;
        float v = acc[m][n][i];
        if (EPI == 1) v = fmaxf(v + bias[col], 0.f);
        if (EPI == 2 || EPI == 5) v = v + bias[col] + res[(size_t)row * N + col];
        if (EPI == 4)
          v = v + bias[col] + (float)((const bf16_t*)res)[(size_t)row * N + col];
        if (EPI == 2 || EPI == 4) {
          ((float*)Cout)[(size_t)row * N + col] = v;
        } else if (EPI == 3) {
          if (col >= 2048) {
            const int hd = col - 2048;  // h*64 + d
            const size_t vidx =
                ((size_t)((row >> 11) * 16 + (hd >> 6)) * 64 + (hd & 63)) * TT + (row & (TT - 1));
            vt[vidx] = (bf16_t)v;
          } else {
            ((bf16_t*)Cout)[(size_t)row * N + col] = (bf16_t)v;
          }
        } else {
          ((bf16_t*)Cout)[(size_t)row * N + col] = (bf16_t)v;
        }
      }
    }
  }
}

// Flash attention, causal, D=64, T=2048 (R16/R24 structure: 4 waves, 64 q-rows/block;
// KVBLK=128; K and V^T cooperatively LDS-staged; best measured config).
__global__ __launch_bounds__(256, 3) void attn_fwd(const bf16_t* __restrict__ qkv,
                                                   const bf16_t* __restrict__ Vt,
                                                   bf16_t* __restrict__ O) {
  const int bh = blockIdx.x;
  const int bb = bh >> 4, hh = bh & 15;
  const int qt = 31 - (int)blockIdx.y;
  const int qbase = qt * 64;
  const int tid = threadIdx.x;
  const int wave = tid >> 6, lane = tid & 63;
  const int lr = lane & 15, lg = lane >> 4;
  const bf16_t* Qp = qkv + (size_t)bb * TT * 3072 + hh * 64;
  const bf16_t* Kp = Qp + 1024;
  const bf16_t* Vh = Vt + (size_t)bh * 64 * TT;

  constexpr int KLP = 72;
  constexpr int VLP = 136;
  constexpr int PLP = 136;
  __shared__ alignas(16) bf16_t Klds[128 * KLP];
  __shared__ alignas(16) bf16_t Vlds[64 * VLP];
  __shared__ alignas(16) bf16_t PlS[4][16 * PLP];
  bf16_t* Pw = PlS[wave];

  const int ksr = wave * 32 + (lane >> 3);
  const int ksc = (lane & 7) * 8;
  const int vsr = wave * 16 + (lane >> 4);
  const int vsc = (lane & 15) * 8;

  const int qrow = qbase + wave * 16;
  bf16x8 qf0, qf1;
  {
    const bf16x8 a = *(const bf16x8*)(Qp + (size_t)(qrow + lr) * 3072 + lg * 8);
    const bf16x8 b = *(const bf16x8*)(Qp + (size_t)(qrow + lr) * 3072 + 32 + lg * 8);
#pragma unroll
    for (int j = 0; j < 8; ++j) {
      qf0[j] = (bf16_t)((float)a[j] * 0.03125f);
      qf1[j] = (bf16_t)((float)b[j] * 0.03125f);
    }
  }

  f32x4 oacc[4] = {};
  float m_r[4], l_r[4];
#pragma unroll
  for (int i = 0; i < 4; ++i) { m_r[i] = -1e38f; l_r[i] = 0.f; }

  bf16x8 kpre[4], vpre[4];
#pragma unroll
  for (int i = 0; i < 4; ++i) {
    kpre[i] = *(const bf16x8*)(Kp + (size_t)(ksr + i * 8) * 3072 + ksc);
    vpre[i] = *(const bf16x8*)(Vh + (size_t)(vsr + i * 4) * TT + vsc);
  }
#pragma unroll
  for (int i = 0; i < 4; ++i) {
    *(bf16x8*)&Klds[(ksr + i * 8) * KLP + ksc] = kpre[i];
    *(bf16x8*)&Vlds[(vsr + i * 4) * VLP + vsc] = vpre[i];
  }
  __syncthreads();

  const int nt = (qt >> 1) + 1;
  for (int t = 0; t < nt; ++t) {
    const int s0 = t * 128;
    const int sn = (t + 1 < nt) ? s0 + 128 : s0;
#pragma unroll
    for (int i = 0; i < 4; ++i) {
      kpre[i] = *(const bf16x8*)(Kp + (size_t)(sn + ksr + i * 8) * 3072 + ksc);
      vpre[i] = *(const bf16x8*)(Vh + (size_t)(vsr + i * 4) * TT + sn + vsc);
    }

    const int u = (qrow - s0) >> 4;
    const int cmc = min(u | 1, 7);

    float P[8][4];
    __builtin_amdgcn_s_setprio(1);
#pragma unroll
    for (int ct = 0; ct < 8; ++ct) {
      if (ct <= cmc) {
        const bf16x8 kf0 = *(const bf16x8*)&Klds[(ct * 16 + lr) * KLP + lg * 8];
        const bf16x8 kf1 = *(const bf16x8*)&Klds[(ct * 16 + lr) * KLP + 32 + lg * 8];
        f32x4 z = {};
        z = __builtin_amdgcn_mfma_f32_16x16x32_bf16(qf0, kf0, z, 0, 0, 0);
        z = __builtin_amdgcn_mfma_f32_16x16x32_bf16(qf1, kf1, z, 0, 0, 0);
        if (ct >= u) {
          const int sg = s0 + ct * 16 + lr;
#pragma unroll
          for (int i = 0; i < 4; ++i)
            P[ct][i] = (sg > qrow + lg * 4 + i) ? -1e30f : z[i];
        } else {
#pragma unroll
          for (int i = 0; i < 4; ++i) P[ct][i] = z[i];
        }
      } else {
#pragma unroll
        for (int i = 0; i < 4; ++i) P[ct][i] = -1e30f;
      }
    }
    __builtin_amdgcn_s_setprio(0);

    float lmax[4];
#pragma unroll
    for (int i = 0; i < 4; ++i) {
      float m0 = fmaxf(fmaxf(P[0][i], P[1][i]), fmaxf(P[2][i], P[3][i]));
      float m1 = fmaxf(fmaxf(P[4][i], P[5][i]), fmaxf(P[6][i], P[7][i]));
      lmax[i] = fmaxf(m0, m1);
    }
    const bool ok = (lmax[0] <= m_r[0] + 8.f) && (lmax[1] <= m_r[1] + 8.f) &&
                    (lmax[2] <= m_r[2] + 8.f) && (lmax[3] <= m_r[3] + 8.f);
    if (!__all(ok)) {
      float rm[4] = {lmax[0], lmax[1], lmax[2], lmax[3]};
#pragma unroll
      for (int off = 1; off < 16; off <<= 1)
#pragma unroll
        for (int i = 0; i < 4; ++i) rm[i] = fmaxf(rm[i], __shfl_xor(rm[i], off));
#pragma unroll
      for (int i = 0; i < 4; ++i) {
        const float mn = fmaxf(m_r[i], rm[i]);
        const float alpha = __expf(m_r[i] - mn);
        m_r[i] = mn;
        l_r[i] *= alpha;
#pragma unroll
        for (int db = 0; db < 4; ++db) oacc[db][i] *= alpha;
      }
    }

#pragma unroll
    for (int i = 0; i < 4; ++i) {
      float ls = 0.f;
#pragma unroll
      for (int ct = 0; ct < 8; ++ct) {
        const float p = __expf(P[ct][i] - m_r[i]);
        P[ct][i] = p;
        ls += p;
      }
      l_r[i] += ls;
    }

#pragma unroll
    for (int ct = 0; ct < 8; ++ct) {
      if (ct <= cmc) {
#pragma unroll
        for (int i = 0; i < 4; ++i) {
          const int q = lg * 4 + i;
          const int col = (ct * 16 + lr) ^ ((lg >> 1) << 4);
          Pw[q * PLP + col] = (bf16_t)P[ct][i];
        }
      }
    }
    asm volatile("s_waitcnt lgkmcnt(0)" ::: "memory");
    __builtin_amdgcn_sched_barrier(0);

    const int kcm = cmc >> 1;
    __builtin_amdgcn_s_setprio(1);
#pragma unroll
    for (int kc = 0; kc < 4; ++kc) {
      if (kc <= kcm) {
        const bf16x8 pf =
            *(const bf16x8*)&Pw[lr * PLP + ((kc * 32 + lg * 8) ^ ((lr >> 3) << 4))];
#pragma unroll
        for (int db = 0; db < 4; ++db) {
          const bf16x8 vf = *(const bf16x8*)&Vlds[(db * 16 + lr) * VLP + kc * 32 + lg * 8];
          oacc[db] = __builtin_amdgcn_mfma_f32_16x16x32_bf16(pf, vf, oacc[db], 0, 0, 0);
        }
      }
    }
    __builtin_amdgcn_s_setprio(0);

    if (t + 1 < nt) {
      __syncthreads();
#pragma unroll
      for (int i = 0; i < 4; ++i) {
        *(bf16x8*)&Klds[(ksr + i * 8) * KLP + ksc] = kpre[i];
        *(bf16x8*)&Vlds[(vsr + i * 4) * VLP + vsc] = vpre[i];
      }
      __syncthreads();
    }
  }

#pragma unroll
  for (int off = 1; off < 16; off <<= 1)
#pragma unroll
    for (int i = 0; i < 4; ++i) l_r[i] += __shfl_xor(l_r[i], off);

  bf16_t* Op = O + ((size_t)bb * TT + qrow) * CC + hh * 64;
#pragma unroll
  for (int i = 0; i < 4; ++i) {
    const float rl = 1.0f / l_r[i];
#pragma unroll
    for (int db = 0; db < 4; ++db)
      Op[(size_t)(lg * 4 + i) * CC + db * 16 + lr] = (bf16_t)(oacc[db][i] * rl);
  }
}

extern "C" void kernel_launch(void* const* d_in, const int* in_sizes, int n_in,
                              void* d_out, int out_size, void* d_ws, size_t ws_size,
                              hipStream_t stream) {
  const float* x      = (const float*)d_in[0];
  const float* wq     = (const float*)d_in[1];
  const float* wk     = (const float*)d_in[2];
  const float* wv     = (const float*)d_in[3];
  const float* w_proj = (const float*)d_in[4];
  const float* b_proj = (const float*)d_in[5];
  const float* w1     = (const float*)d_in[6];
  const float* b1     = (const float*)d_in[7];
  const float* w2     = (const float*)d_in[8];
  const float* b2     = (const float*)d_in[9];
  const float* ln1_g  = (const float*)d_in[10];
  const float* ln1_b  = (const float*)d_in[11];
  const float* ln2_g  = (const float*)d_in[12];
  const float* ln2_b  = (const float*)d_in[13];

  char* ws = (char*)d_ws;
  const size_t MB = 1024 * 1024;
  bf16_t* h1    = (bf16_t*)(ws + 0);         // 8 MB  [4096][1024]
  bf16_t* Bqkv  = (bf16_t*)(ws + 8 * MB);    // 6 MB  [3072][1024]
  bf16_t* Bproj = (bf16_t*)(ws + 14 * MB);   // 2 MB  [1024][1024]
  bf16_t* B1w   = (bf16_t*)(ws + 16 * MB);   // 8 MB  [4096][1024]
  bf16_t* B2w   = (bf16_t*)(ws + 24 * MB);   // 8 MB  [1024][4096]
  bf16_t* qkv   = (bf16_t*)(ws + 32 * MB);   // 24 MB [4096][3072] (V region unused)
  bf16_t* Obuf  = (bf16_t*)(ws + 56 * MB);   // 8 MB  [4096][1024]
  bf16_t* res1b = (bf16_t*)(ws + 64 * MB);   // 8 MB  [4096][1024] bf16, written AFTER attn
  bf16_t* Vt    = (bf16_t*)(ws + 64 * MB);   // 16 MB [32][64][2048], dead once attn done
  bf16_t* h2    = (bf16_t*)(ws + 80 * MB);   // 8 MB  [4096][1024]
  bf16_t* a1    = (bf16_t*)(ws + 32 * MB);   // 32 MB [4096][4096], reuses qkv+Obuf
  float*  outp  = (float*)d_out;

  dim3 blk(256), blk512(512);
  prep_all<<<dim3(16384), blk, 0, stream>>>(wq, wk, wv, w_proj, w1, w2,
                                            Bqkv, Bproj, B1w, B2w,
                                            x, ln1_g, ln1_b, h1);

  gemm_bt<3, 128, 128, 2, 8><<<dim3(24, 32), blk512, 0, stream>>>(h1, Bqkv, qkv, nullptr,
                                                                  nullptr, Vt, 4096, 3072, 1024);
  attn_fwd<<<dim3(32, 32), blk, 0, stream>>>(qkv, Vt, Obuf);
  gemm_bt<5, 64, 64, 2, 4><<<dim3(16, 64), blk, 0, stream>>>(Obuf, Bproj, res1b, b_proj, x,
                                                             nullptr, 4096, 1024, 1024);
  ln_bf16_bf16<<<dim3(4096), blk, 0, stream>>>(res1b, ln2_g, ln2_b, h2);
  gemm_bt<1, 128, 128, 2, 8><<<dim3(32, 32), blk512, 0, stream>>>(h2, B1w, a1, b1, nullptr,
                                                                  nullptr, 4096, 4096, 1024);
  gemm_bt<4, 64, 64, 2, 4><<<dim3(16, 64), blk, 0, stream>>>(a1, B2w, outp, b2,
                                                             (const float*)res1b,
                                                             nullptr, 4096, 1024, 4096);
}